// Round 4
// baseline (6808.369 us; speedup 1.0000x reference)
//
#include <hip/hip_runtime.h>
#include <hip/hip_bf16.h>
#include <stdint.h>

// ---------------------------------------------------------------------------
// GRU over sequence. B=64, T=512, D=1024, H=1024.
//   Precompute: xproj[m][0:2048]   = x@W[:D] + W_b   (m = b*T + t)
//               xproj[m][2048:3072]= x@U[:D] + U_b
//   Sequential: persistent 64 blocks x 512 thr. 4 independent chains
//   (mh = b&3, 16 rows each), 16 blocks per chain.
//   v6: FLAGLESS exchange. Producers store bf16-packed u64 payloads directly
//   into each consumer block's PRIVATE mailbox (16 copies); consumers poll
//   the data itself against the sentinel 0xFFFF... (bf16 NaN, never produced)
//   and reset their copy after reading. Double-buffered by t&1. Exchange =
//   store-flight + one LLC detect RT (was: drain + flag RT + poll RT +
//   data RT). Mailboxes (8MB) overlay the dead xbf region. One grid barrier
//   after prologue init; per-step sync is s_barrier + data polls only.
// ---------------------------------------------------------------------------

typedef unsigned short u16;
typedef unsigned long long u64;
typedef __attribute__((ext_vector_type(8))) short bf16x8;
typedef __attribute__((ext_vector_type(4))) float f32x4;

constexpr int Bsz = 64, Tt = 512, Dd = 1024, Hh = 1024;
constexpr int Mrows = Bsz * Tt;   // 32768
constexpr int NP = 3 * Hh;        // 3072
constexpr int NBLK = 64, THR = 512;
constexpr u64 SENTV = ~0ull;

// workspace layout (bytes)
constexpr size_t SZ_XPROJ = (size_t)Mrows * NP * 2;   // 201326592
constexpr size_t SZ_XBF   = (size_t)Mrows * Dd * 2;   //  67108864
constexpr size_t SZ_PT    = (size_t)NP * 1024 * 2;    //   6291456
constexpr size_t SZ_WHT   = (size_t)2048 * 1024 * 2;  //   4194304
constexpr size_t SZ_UHT   = (size_t)1024 * 1024 * 2;  //   2097152
constexpr size_t OFF_XPROJ = 0;
constexpr size_t OFF_XBF   = OFF_XPROJ + SZ_XPROJ;
constexpr size_t OFF_PT    = OFF_XBF + SZ_XBF;
constexpr size_t OFF_WHT   = OFF_PT + SZ_PT;
constexpr size_t OFF_UHT   = OFF_WHT + SZ_WHT;
constexpr size_t OFF_BAR   = OFF_UHT + SZ_UHT;          // 64 flags x 64B
constexpr size_t WS_NEEDED = OFF_BAR + 4096;
// mailboxes overlay XBF (xbf is dead once k_gemm finishes; k_seq prologue
// re-initializes every slot, so stale bytes across launches are harmless):
//   h_pv : [64 blk][2 parity][4096] u64 = 4MB   (h    exchange)
//   rh_pv: [64 blk][2 parity][4096] u64 = 4MB   (rh   exchange)
constexpr size_t OFF_HPV = OFF_XBF;
constexpr size_t OFF_RPV = OFF_XBF + 4194304;

__device__ __forceinline__ float b2f(u16 u) {
  union { unsigned i; float f; } x; x.i = ((unsigned)u) << 16; return x.f;
}
__device__ __forceinline__ u16 f2b(float f) {
  union { float f; unsigned i; } x; x.f = f;
  unsigned r = (x.i >> 16) & 1u;
  return (u16)((x.i + 0x7fffu + r) >> 16);
}
__device__ __forceinline__ float sigmoidf_(float x) { return 1.0f / (1.0f + __expf(-x)); }
__device__ __forceinline__ float tanhf_(float x) { return 1.0f - 2.0f / (__expf(2.0f * x) + 1.0f); }

__device__ __forceinline__ u64 ldA_u64(const u64* p) {
  return __hip_atomic_load(p, __ATOMIC_RELAXED, __HIP_MEMORY_SCOPE_AGENT);
}
__device__ __forceinline__ void stA_u64(u64* p, u64 v) {
  __hip_atomic_store(p, v, __ATOMIC_RELAXED, __HIP_MEMORY_SCOPE_AGENT);
}
__device__ __forceinline__ unsigned ldA_u32(const unsigned* p) {
  return __hip_atomic_load(p, __ATOMIC_RELAXED, __HIP_MEMORY_SCOPE_AGENT);
}
__device__ __forceinline__ void stA_u32(unsigned* p, unsigned v) {
  __hip_atomic_store(p, v, __ATOMIC_RELAXED, __HIP_MEMORY_SCOPE_AGENT);
}

// targeted sync primitives (asm "memory" clobber = compiler fence)
__device__ __forceinline__ void drain_vm() {            // wait own vmem only
  asm volatile("s_waitcnt vmcnt(0)" ::: "memory");
}
__device__ __forceinline__ void bar_lds() {             // LDS-producer barrier
  asm volatile("s_waitcnt lgkmcnt(0)\n\ts_barrier" ::: "memory");
}
__device__ __forceinline__ void bar_x() {               // plain join, NO drain
  asm volatile("s_barrier" ::: "memory");
}

// async global->LDS, 16B per lane (used by k_gemm only)
__device__ __forceinline__ void gl2lds16(const void* g, void* l) {
  __builtin_amdgcn_global_load_lds(
      (const __attribute__((address_space(1))) void*)g,
      (__attribute__((address_space(3))) void*)l, 16, 0, 0);
}

// ------------------------------- prep kernels ------------------------------
__global__ void k_prep_x(const float* __restrict__ x, u16* __restrict__ xbf,
                         unsigned* __restrict__ bar) {
  size_t i = (size_t)blockIdx.x * blockDim.x + threadIdx.x;
  size_t stride = (size_t)gridDim.x * blockDim.x;
  if (i < 1024) bar[i] = 0u;   // 64 flag lines (16 u32 each)
  for (size_t k = i; k < (size_t)Mrows * Dd; k += stride) xbf[k] = f2b(x[k]);
}

// coalesced reads: grid (24, 1024), block 256. blockIdx.y = k.
__global__ void k_prep_w(const float* __restrict__ W, const float* __restrict__ U,
                         u16* __restrict__ Pt, u16* __restrict__ Wht, u16* __restrict__ Uht) {
  int k = blockIdx.y, xb = blockIdx.x, tid = threadIdx.x;
  if (xb < 12) {            // Pt[n][k], n 0..3071
    int n = xb * 256 + tid;
    float v = (n < 2048) ? W[(size_t)k * 2048 + n] : U[(size_t)k * 1024 + (n - 2048)];
    Pt[(size_t)n * 1024 + k] = f2b(v);
  } else if (xb < 20) {     // Wht[n][k] = W[1024+k][n], n 0..2047
    int n = (xb - 12) * 256 + tid;
    Wht[(size_t)n * 1024 + k] = f2b(W[(size_t)(1024 + k) * 2048 + n]);
  } else {                  // Uht[n][k] = U[1024+k][n], n 0..1023
    int n = (xb - 20) * 256 + tid;
    Uht[(size_t)n * 1024 + k] = f2b(U[(size_t)(1024 + k) * 1024 + n]);
  }
}

__global__ void k_ws_too_small(float* out) {
  out[threadIdx.x] = 12345.0f;  // sentinel: ws_size < WS_NEEDED
}

// --------------------------- precompute GEMM (m97) -------------------------
__global__ void k_gemm(const u16* __restrict__ xbf, const u16* __restrict__ Pt,
                       const float* __restrict__ Wb, const float* __restrict__ Ub,
                       u16* __restrict__ xproj) {
  __shared__ u16 As[128 * 32];
  __shared__ u16 Bs[128 * 32];
  const int tid = threadIdx.x, lane = tid & 63, w = tid >> 6;
  const int l15 = lane & 15, q = lane >> 4;
  const int bm = blockIdx.x, bn = blockIdx.y;
  const int wm = w >> 1, wn = w & 1;
  const int lr = lane >> 2;
  const int lc = (lane & 3) * 8;
  f32x4 acc[4][4] = {};
  for (int kt = 0; kt < 32; ++kt) {
    __syncthreads();
    {
      const u16* ga = xbf + (size_t)(bm * 128 + w * 32 + lr) * 1024 + kt * 32 + lc;
      gl2lds16(ga, As + w * 1024);
      gl2lds16(ga + 16 * 1024, As + w * 1024 + 512);
      const u16* gb = Pt + (size_t)(bn * 128 + w * 32 + lr) * 1024 + kt * 32 + lc;
      gl2lds16(gb, Bs + w * 1024);
      gl2lds16(gb + 16 * 1024, Bs + w * 1024 + 512);
    }
    __syncthreads();
    bf16x8 af[4], bfr[4];
#pragma unroll
    for (int i = 0; i < 4; ++i)
      af[i] = *(const bf16x8*)(As + (wm * 64 + i * 16 + l15) * 32 + q * 8);
#pragma unroll
    for (int j = 0; j < 4; ++j)
      bfr[j] = *(const bf16x8*)(Bs + (wn * 64 + j * 16 + l15) * 32 + q * 8);
#pragma unroll
    for (int i = 0; i < 4; ++i)
#pragma unroll
      for (int j = 0; j < 4; ++j)
        acc[i][j] = __builtin_amdgcn_mfma_f32_16x16x32_bf16(af[i], bfr[j], acc[i][j], 0, 0, 0);
  }
#pragma unroll
  for (int j = 0; j < 4; ++j) {
    int n = bn * 128 + wn * 64 + j * 16 + l15;
    float bias = (n < 2048) ? Wb[n] : Ub[n - 2048];
#pragma unroll
    for (int i = 0; i < 4; ++i) {
#pragma unroll
      for (int r = 0; r < 4; ++r) {
        int m = bm * 128 + wm * 64 + i * 16 + q * 4 + r;
        xproj[(size_t)m * NP + n] = f2b(acc[i][j][r] + bias);
      }
    }
  }
}

// ---------------------- mailbox staging with data-poll ---------------------
// Mailbox layout per (block,parity): [1024 col][4 qq] u64; slot col*4+qq holds
// rows 4qq..4qq+3 (bf16) of that col. Per thread: 8 slots (2 iters x 4 cols),
// poll until != SENT, transpose-pack to hs rows, reset slots to SENT.
__device__ __forceinline__ void stage_poll(u64* g, u16* hs, int tid) {
  u64 vv0[4], vv1[4];
  const int z0 = tid, z1 = THR + tid;
  const int rr0 = z0 & 3, cq0 = z0 >> 2;
  const int rr1 = z1 & 3, cq1 = z1 >> 2;
  u64* p0 = g + cq0 * 16 + rr0;
  u64* p1 = g + cq1 * 16 + rr1;
  vv0[0] = ldA_u64(p0); vv0[1] = ldA_u64(p0 + 4);
  vv0[2] = ldA_u64(p0 + 8); vv0[3] = ldA_u64(p0 + 12);
  vv1[0] = ldA_u64(p1); vv1[1] = ldA_u64(p1 + 4);
  vv1[2] = ldA_u64(p1 + 8); vv1[3] = ldA_u64(p1 + 12);
  for (;;) {
    bool any = false;
#pragma unroll
    for (int k = 0; k < 4; ++k) {
      if (vv0[k] == SENTV) { vv0[k] = ldA_u64(p0 + 4 * k); if (vv0[k] == SENTV) any = true; }
      if (vv1[k] == SENTV) { vv1[k] = ldA_u64(p1 + 4 * k); if (vv1[k] == SENTV) any = true; }
    }
    if (!any) break;
  }
#pragma unroll
  for (int k = 0; k < 4; ++k) {
    int r0 = rr0 * 4 + k;
    u64 w0 = (u64)(u16)(vv0[0] >> (16 * k)) | ((u64)(u16)(vv0[1] >> (16 * k)) << 16)
           | ((u64)(u16)(vv0[2] >> (16 * k)) << 32) | ((u64)(u16)(vv0[3] >> (16 * k)) << 48);
    *(u64*)(hs + r0 * 1032 + cq0 * 4) = w0;
    int r1 = rr1 * 4 + k;
    u64 w1 = (u64)(u16)(vv1[0] >> (16 * k)) | ((u64)(u16)(vv1[1] >> (16 * k)) << 16)
           | ((u64)(u16)(vv1[2] >> (16 * k)) << 32) | ((u64)(u16)(vv1[3] >> (16 * k)) << 48);
    *(u64*)(hs + r1 * 1032 + cq1 * 4) = w1;
  }
  // reset private copy for the parity's next use (t+2); drained before the
  // thread's next publish, which causally precedes the producer's rewrite.
  stA_u64(p0, SENTV); stA_u64(p0 + 4, SENTV); stA_u64(p0 + 8, SENTV); stA_u64(p0 + 12, SENTV);
  stA_u64(p1, SENTV); stA_u64(p1 + 4, SENTV); stA_u64(p1 + 8, SENTV); stA_u64(p1 + 12, SENTV);
}

// ------------------------------ sequential scan ----------------------------
// 64 blocks x 512 thr (8 waves). Block owns 16 batch rows (mh = b&3).
// Odd waves:  phase-A r-tile (cols 0..1023) -> rh publish to 16 mailboxes;
//             phase-B K-half 1 partial.
// Even waves: phase-A u-tile == phase-B c-tile (u stays in regs);
//             phase-B K-half 0 + finish + h publish to 16 mailboxes.
__global__ void __launch_bounds__(THR, 1)
k_seq(const u16* __restrict__ xproj, const u16* __restrict__ Wht,
      const u16* __restrict__ Uht, const float* __restrict__ h0,
      u64* __restrict__ h_pv, u64* __restrict__ rh_pv,
      float* __restrict__ out, unsigned* __restrict__ bar) {
  __shared__ u16 hs[16 * 1032];      // staged h or rh, row-major, pad 8
  __shared__ f32x4 red[4][64];       // phase-B split-K reduction
  const int tid = threadIdx.x, lane = tid & 63, w = tid >> 6;
  const int l15 = lane & 15, q = lane >> 4;
  const int b = blockIdx.x;
  const int mh = b & 3;              // 16-row batch group (independent chain)
  const int rbase = mh * 16;
  const int bq = b >> 2;             // 0..15 (position within group)
  const int half = w >> 1;           // 0..3
  const int odd = w & 1;             // phase-B K-half; phase-A r(1)/u(0) role
  const int a_nt = odd ? (bq * 4 + half) : (64 + bq * 4 + half);
  const int a_col = a_nt * 16 + l15;         // odd: 0..1023, even: 1024..2047
  const int b_col = (bq * 4 + half) * 16 + l15;  // 0..1023

  // ---- recurrent weights -> registers for the whole scan ----
  bf16x8 wa[32];
  { const u16* p = Wht + (size_t)a_col * 1024 + q * 8;
#pragma unroll
    for (int s = 0; s < 32; ++s) wa[s] = *(const bf16x8*)(p + s * 32); }
  bf16x8 wb[16];
  { const u16* p = Uht + (size_t)b_col * 1024 + odd * 512 + q * 8;
#pragma unroll
    for (int s = 0; s < 16; ++s) wb[s] = *(const bf16x8*)(p + s * 32); }

  // fp32 hidden-state carry: even waves own rows rbase+q*4+r, col b_col
  float hp[4];
#pragma unroll
  for (int r = 0; r < 4; ++r) hp[r] = h0[(size_t)(rbase + q * 4 + r) * 1024 + b_col];

  // prefetch gx (phase A) and ux (phase B, even only) for t=0
  float gxp[4];
#pragma unroll
  for (int r = 0; r < 4; ++r)
    gxp[r] = b2f(xproj[(size_t)((rbase + q * 4 + r) * Tt + 0) * NP + a_col]);
  float uxp[4] = {0.f, 0.f, 0.f, 0.f};
  if (!odd) {
#pragma unroll
    for (int r = 0; r < 4; ++r)
      uxp[r] = b2f(xproj[(size_t)((rbase + q * 4 + r) * Tt + 0) * NP + 2048 + b_col]);
  }

  // ---- prologue: init OWN mailboxes (parity0 h = packed h0; rest = SENT) ---
  u64* myh = h_pv + (size_t)b * 8192;     // [2][4096]
  u64* myr = rh_pv + (size_t)b * 8192;
  for (int z = tid; z < 4096; z += THR) {
    int col = z >> 2, qq = z & 3;
    u64 v = 0;
#pragma unroll
    for (int k = 0; k < 4; ++k)
      v |= (u64)f2b(h0[(size_t)(rbase + qq * 4 + k) * 1024 + col]) << (16 * k);
    stA_u64(myh + z, v);
    stA_u64(myh + 4096 + z, SENTV);
    stA_u64(myr + z, SENTV);
    stA_u64(myr + 4096 + z, SENTV);
  }
  // one-time grid barrier: all mailbox inits at LLC before any cross-block
  // publish can land (k_prep_x zeroed the flag lines).
  __syncthreads();                      // full drain OK here (one-time)
  if (tid == 0) stA_u32(bar + (b << 4), 1u);
  if (tid < 64) { while (ldA_u32(bar + (tid << 4)) < 1u) {} }
  __syncthreads();

#pragma unroll 1
  for (int t = 0; t < Tt; ++t) {
    const int p = t & 1;
    // ---- stage h from own mailbox (data-poll, reset) ----
    stage_poll(myh + p * 4096, hs, tid);
    bar_lds();   // ds_writes visible block-wide; nothing else drained

    // ---- phase A: gi tile = h @ Wh[:,a_col tile], K=1024, 2 acc chains ----
    f32x4 acc = {0.f, 0.f, 0.f, 0.f}, acc2 = {0.f, 0.f, 0.f, 0.f};
    {
      const u16* hb = hs + l15 * 1032 + q * 8;
#pragma unroll
      for (int s = 0; s < 32; s += 2) {
        bf16x8 a0 = *(const bf16x8*)(hb + s * 32);
        bf16x8 a1 = *(const bf16x8*)(hb + (s + 1) * 32);
        acc  = __builtin_amdgcn_mfma_f32_16x16x32_bf16(a0, wa[s], acc, 0, 0, 0);
        acc2 = __builtin_amdgcn_mfma_f32_16x16x32_bf16(a1, wa[s + 1], acc2, 0, 0, 0);
      }
      acc += acc2;
    }
    float uvr[4];
    if (odd) {         // r-columns: rh = sigmoid(gi)*h -> publish to 16 boxes
      u64 pk = 0;
#pragma unroll
      for (int r = 0; r < 4; ++r) {
        int lrow = q * 4 + r;
        float g = sigmoidf_(acc[r] + gxp[r]);
        float hcell = b2f(hs[lrow * 1032 + a_col]);
        pk |= (u64)f2b(g * hcell) << (16 * r);
      }
      drain_vm();      // order earlier mailbox resets ahead of this publish
      const size_t slot = (size_t)p * 4096 + a_col * 4 + q;
#pragma unroll
      for (int j = 0; j < 16; ++j)
        stA_u64(rh_pv + (size_t)(4 * j + mh) * 8192 + slot, pk);
    } else {           // u-columns: SAME tile as phase B -> stays in regs
#pragma unroll
      for (int r = 0; r < 4; ++r) uvr[r] = sigmoidf_(acc[r] + gxp[r]);
    }
    bar_x();           // hs phase-A reads complete before stage-rh overwrites

    // ---- stage rh from own mailbox (data-poll, reset) ----
    stage_poll(myr + p * 4096, hs, tid);
    bar_lds();

    // ---- phase B: c tile = rh @ Uh[:,b_col tile], K split 2, 2 acc chains ----
    f32x4 accb = {0.f, 0.f, 0.f, 0.f}, accb2 = {0.f, 0.f, 0.f, 0.f};
    {
      const u16* rb = hs + l15 * 1032 + odd * 512 + q * 8;
#pragma unroll
      for (int s = 0; s < 16; s += 2) {
        bf16x8 a0 = *(const bf16x8*)(rb + s * 32);
        bf16x8 a1 = *(const bf16x8*)(rb + (s + 1) * 32);
        accb  = __builtin_amdgcn_mfma_f32_16x16x32_bf16(a0, wb[s], accb, 0, 0, 0);
        accb2 = __builtin_amdgcn_mfma_f32_16x16x32_bf16(a1, wb[s + 1], accb2, 0, 0, 0);
      }
      accb += accb2;
    }
    if (odd) red[half][lane] = accb;
    bar_lds();   // red visible; no vmcnt drain
    if (!odd) {
      accb += red[half][lane];
      float hn_[4];
      u64 pk = 0;
#pragma unroll
      for (int r = 0; r < 4; ++r) {
        float c = tanhf_(accb[r] + uxp[r]);
        float hn = uvr[r] * hp[r] + (1.0f - uvr[r]) * c;
        hp[r] = hn; hn_[r] = hn;
        pk |= (u64)f2b(hn) << (16 * r);
      }
      drain_vm();      // order earlier mailbox resets ahead of this publish
      const size_t slot = (size_t)((t + 1) & 1) * 4096 + b_col * 4 + q;
#pragma unroll
      for (int j = 0; j < 16; ++j)
        stA_u64(h_pv + (size_t)(4 * j + mh) * 8192 + slot, pk);
      // out stores after publish -> never on the exchange critical path
#pragma unroll
      for (int r = 0; r < 4; ++r)
        out[((size_t)(rbase + q * 4 + r) * Tt + t) * 1024 + b_col] = hn_[r];
    }
    if (t + 1 < Tt) {  // prefetch next gx/ux (read-only, plain cached)
#pragma unroll
      for (int r = 0; r < 4; ++r)
        gxp[r] = b2f(xproj[(size_t)((rbase + q * 4 + r) * Tt + (t + 1)) * NP + a_col]);
      if (!odd) {
#pragma unroll
        for (int r = 0; r < 4; ++r)
          uxp[r] = b2f(xproj[(size_t)((rbase + q * 4 + r) * Tt + (t + 1)) * NP + 2048 + b_col]);
      }
    }
  }
}

// --------------------------------- launch ----------------------------------
extern "C" void kernel_launch(void* const* d_in, const int* in_sizes, int n_in,
                              void* d_out, int out_size, void* d_ws, size_t ws_size,
                              hipStream_t stream) {
  const float* x  = (const float*)d_in[0];
  const float* h0 = (const float*)d_in[1];
  const float* W  = (const float*)d_in[2];
  const float* Wb = (const float*)d_in[3];
  const float* U  = (const float*)d_in[4];
  const float* Ub = (const float*)d_in[5];
  float* out = (float*)d_out;

  if (ws_size < WS_NEEDED) {
    k_ws_too_small<<<1, 256, 0, stream>>>(out);
    return;
  }

  char* ws = (char*)d_ws;
  u16* xproj = (u16*)(ws + OFF_XPROJ);
  u16* xbf   = (u16*)(ws + OFF_XBF);
  u16* Pt    = (u16*)(ws + OFF_PT);
  u16* Wht   = (u16*)(ws + OFF_WHT);
  u16* Uht   = (u16*)(ws + OFF_UHT);
  u64* h_pv  = (u64*)(ws + OFF_HPV);
  u64* rh_pv = (u64*)(ws + OFF_RPV);
  unsigned* bar = (unsigned*)(ws + OFF_BAR);

  k_prep_x<<<2048, 256, 0, stream>>>(x, xbf, bar);
  k_prep_w<<<dim3(24, 1024), 256, 0, stream>>>(W, U, Pt, Wht, Uht);
  k_gemm<<<dim3(256, 24), 256, 0, stream>>>(xbf, Pt, Wb, Ub, xproj);
  k_seq<<<NBLK, 512, 0, stream>>>(xproj, Wht, Uht, h0, h_pv, rh_pv, out, bar);
}